// Round 2
// baseline (260.160 us; speedup 1.0000x reference)
//
#include <hip/hip_runtime.h>
#include <hip/hip_bf16.h>
#include <stdint.h>

#define N_ELx 768
#define EMBx 128
#define TPSx 64
#define EDGE_INx 32
#define EPB 128
#define NBINS 2304   // 3 types * 768 receivers

typedef __attribute__((ext_vector_type(8))) short bf16x8;
typedef __attribute__((ext_vector_type(4))) float f32x4;

__device__ __forceinline__ short f2bf(float f) {
    union { float f; uint32_t u; } v; v.f = f;
    uint32_t u = v.u;
    uint32_t r = (u + 0x7FFFu + ((u >> 16) & 1u)) >> 16;
    return (short)r;
}

__device__ __forceinline__ float silu_f(float x) {
    return x / (1.0f + __expf(-x));
}

// ---------------- prep kernel: hx tables + B-fragment packing ----------------
__global__ __launch_bounds__(256)
void prep_kernel(const float* __restrict__ elec, const float* __restrict__ nuclei,
                 const float* __restrict__ uW, const float* __restrict__ wW,
                 const float* __restrict__ hWee, const float* __restrict__ hbee,
                 const float* __restrict__ hWne, const float* __restrict__ hbne,
                 float* __restrict__ hx0, float* __restrict__ hx1, float* __restrict__ hxn,
                 short* __restrict__ uWfrag, short* __restrict__ wWfrag)
{
    int b = blockIdx.x;
    int tid = threadIdx.x;
    if (b < 384) {
        // hx0 / hx1: silu(E @ hWee[t] + hbee[t]),  768x128 @ 128x64
        int t = b / 192;
        int rb = b % 192;
        int lr = tid >> 6;       // 0..3 (one row per wave)
        int col = tid & 63;
        int row = rb * 4 + lr;
        const float* W = hWee + t * 128 * 64;
        float acc = 0.f;
        for (int k = 0; k < 128; ++k)
            acc += elec[row * 128 + k] * W[k * 64 + col];
        float v = silu_f(acc + hbee[t * 64 + col]);
        (t == 0 ? hx0 : hx1)[row * 64 + col] = v;
    } else if (b == 384) {
        // hxn: silu(nuclei @ hWne + hbne), 32x64 @ 64x64
        int lr = tid >> 6, col = tid & 63;
        for (int i = 0; i < 8; ++i) {
            int row = lr * 8 + i;
            float acc = 0.f;
            for (int k = 0; k < 64; ++k)
                acc += nuclei[row * 64 + k] * hWne[k * 64 + col];
            hxn[row * 64 + col] = silu_f(acc + hbne[col]);
        }
    } else {
        // MFMA B-fragment packing (16x16x32: lane l holds B[k][col],
        // col = ct*16 + (l&15), k = (l>>4)*8 + j)
        for (int idx = tid; idx < 3 * 4 * 64; idx += 256) {
            int lane = idx & 63, ct = (idx >> 6) & 3, ty = idx >> 8;
            for (int j = 0; j < 8; ++j) {
                int k = (lane >> 4) * 8 + j, col = ct * 16 + (lane & 15);
                uWfrag[idx * 8 + j] = f2bf(uW[(ty * 32 + k) * 64 + col]);
            }
        }
        for (int idx = tid; idx < 3 * 2 * 4 * 64; idx += 256) {
            int lane = idx & 63, ct = (idx >> 6) & 3, ks = (idx >> 8) & 1, ty = idx >> 9;
            for (int j = 0; j < 8; ++j) {
                int k = ks * 32 + (lane >> 4) * 8 + j, col = ct * 16 + (lane & 15);
                wWfrag[idx * 8 + j] = f2bf(wW[(ty * 64 + k) * 64 + col]);
            }
        }
    }
}

// ---------------- sort kernels: counting sort of edge ids by receiver ----------
__global__ __launch_bounds__(256)
void hist_kernel(const int* __restrict__ r0, const int* __restrict__ r1,
                 const int* __restrict__ r2,
                 int n0, int n1, int n2, int* __restrict__ bins)
{
    __shared__ int h[NBINS];
    int tid = threadIdx.x;
    for (int i = tid; i < NBINS; i += 256) h[i] = 0;
    __syncthreads();
    int total = n0 + n1 + n2;
    for (int i = blockIdx.x * 256 + tid; i < total; i += gridDim.x * 256) {
        int t, j;
        if (i < n0)            { t = 0; j = i; }
        else if (i < n0 + n1)  { t = 1; j = i - n0; }
        else                   { t = 2; j = i - n0 - n1; }
        int rv = (t == 0 ? r0 : (t == 1 ? r1 : r2))[j];
        atomicAdd(&h[t * 768 + rv], 1);
    }
    __syncthreads();
    for (int i = tid; i < NBINS; i += 256)
        if (h[i]) atomicAdd(&bins[i], h[i]);
}

__global__ __launch_bounds__(256)
void scan_kernel(const int* __restrict__ bins, int* __restrict__ cursor)
{
    __shared__ int part[256];
    int tid = threadIdx.x;
    int l[9]; int s = 0;
    #pragma unroll
    for (int j = 0; j < 9; ++j) { l[j] = bins[tid * 9 + j]; s += l[j]; }
    part[tid] = s;
    __syncthreads();
    for (int off = 1; off < 256; off <<= 1) {
        int v = (tid >= off) ? part[tid - off] : 0;
        __syncthreads();
        part[tid] += v;
        __syncthreads();
    }
    int run = (tid == 0) ? 0 : part[tid - 1];
    #pragma unroll
    for (int j = 0; j < 9; ++j) { cursor[tid * 9 + j] = run; run += l[j]; }
}

__global__ __launch_bounds__(256)
void scatter_kernel(const int* __restrict__ r0, const int* __restrict__ r1,
                    const int* __restrict__ r2,
                    int n0, int n1, int n2,
                    int* __restrict__ cursor, int* __restrict__ perm)
{
    int total = n0 + n1 + n2;
    for (int i = blockIdx.x * 256 + threadIdx.x; i < total; i += gridDim.x * 256) {
        int t, j;
        if (i < n0)            { t = 0; j = i; }
        else if (i < n0 + n1)  { t = 1; j = i - n0; }
        else                   { t = 2; j = i - n0 - n1; }
        int rv = (t == 0 ? r0 : (t == 1 ? r1 : r2))[j];
        int pos = atomicAdd(&cursor[t * 768 + rv], 1);
        perm[pos] = j;
    }
}

// ---------------- edge kernel: receiver-sorted, LDS-aggregated scatter --------
__global__ __launch_bounds__(256)
void edge_kernel(const float* __restrict__ feat0, const float* __restrict__ feat1,
                 const float* __restrict__ feat2,
                 const int* __restrict__ s0, const int* __restrict__ s1, const int* __restrict__ s2,
                 const int* __restrict__ r0, const int* __restrict__ r1, const int* __restrict__ r2,
                 const float* __restrict__ u_b, const float* __restrict__ w_b,
                 const float* __restrict__ hx0, const float* __restrict__ hx1,
                 const float* __restrict__ hxn,
                 const short* __restrict__ uWfrag, const short* __restrict__ wWfrag,
                 const int* __restrict__ perm,
                 float* __restrict__ z,
                 int n0, int n1, int n2, int nb0, int nb1)
{
    // LDS: msg[128][64] f32 (32KB) overlays a1 (8KB @0) + e (16KB @8KB)
    __shared__ __align__(16) char smem[32768 + 1024];
    short* lds_a1 = (short*)smem;              // [4][128][8] bf16
    short* lds_e  = (short*)(smem + 8192);     // [8][128][8] bf16
    float* msg    = (float*)smem;              // [128][64] f32 (after GEMM2)
    int* sidx = (int*)(smem + 32768);
    int* ridx = sidx + 128;

    int b = blockIdx.x;
    int t; const float* feat; const int* sn; const int* rc; const float* hx; int nE;
    if (b < nb0)            { t = 0; feat = feat0; sn = s0; rc = r0; hx = hx0; nE = n0; }
    else if (b < nb0 + nb1) { t = 1; b -= nb0; feat = feat1; sn = s1; rc = r1; hx = hx1; nE = n1; }
    else                    { t = 2; b -= nb0 + nb1; feat = feat2; sn = s2; rc = r2; hx = hxn; nE = n2; }
    int e0 = b * EPB;
    int t_off = (t == 0) ? 0 : (t == 1 ? n0 : n0 + n1);
    float* zt = z + t * (N_ELx * TPSx);

    int tid = threadIdx.x;
    // stage feat -> LDS (bf16, MFMA-A chunk layout), via receiver-sorted perm
    {
        int row = tid >> 1, half = tid & 1;
        bool ok = (e0 + row) < nE;
        int pe = ok ? perm[t_off + e0 + row] : 0;
        if (half == 0) sidx[row] = sn[pe];
        else           ridx[row] = ok ? rc[pe] : 0;
        const float4* src = (const float4*)(feat + (size_t)pe * EDGE_INx + half * 16);
        #pragma unroll
        for (int c = 0; c < 2; ++c) {
            float4 fa, fb;
            if (ok) { fa = src[c * 2 + 0]; fb = src[c * 2 + 1]; }
            else    { fa = make_float4(0,0,0,0); fb = make_float4(0,0,0,0); }
            bf16x8 v;
            v[0] = f2bf(fa.x); v[1] = f2bf(fa.y); v[2] = f2bf(fa.z); v[3] = f2bf(fa.w);
            v[4] = f2bf(fb.x); v[5] = f2bf(fb.y); v[6] = f2bf(fb.z); v[7] = f2bf(fb.w);
            int kc = half * 2 + c;
            *(bf16x8*)&lds_a1[(kc * EPB + row) * 8] = v;
        }
    }
    __syncthreads();

    int lane = tid & 63;
    int w = tid >> 6;          // wave id = output col-tile
    int kc = lane >> 4;        // 0..3
    int cr = lane & 15;
    int col = w * 16 + cr;

    f32x4 zero4 = {0.f, 0.f, 0.f, 0.f};

    // GEMM1: e[128x64] = feat[128x32] @ uW[32x64]
    bf16x8 bu = *(const bf16x8*)(uWfrag + ((t * 4 + w) * 64 + lane) * 8);
    float ubc = u_b[t * 64 + col];
    f32x4 d1[8];
    #pragma unroll
    for (int rt = 0; rt < 8; ++rt) {
        bf16x8 a = *(const bf16x8*)&lds_a1[(kc * EPB + rt * 16 + cr) * 8];
        d1[rt] = __builtin_amdgcn_mfma_f32_16x16x32_bf16(a, bu, zero4, 0, 0, 0);
    }
    // silu + write e to LDS (A-layout for GEMM2; k-dim of GEMM2 = col of e)
    {
        int ks = col >> 5, c2 = (col >> 3) & 3, j = col & 7;
        short* ebase = &lds_e[((ks * 4 + c2) * EPB) * 8 + j];
        #pragma unroll
        for (int rt = 0; rt < 8; ++rt) {
            #pragma unroll
            for (int r = 0; r < 4; ++r) {
                int row = rt * 16 + kc * 4 + r;
                ebase[row * 8] = f2bf(silu_f(d1[rt][r] + ubc));
            }
        }
    }
    __syncthreads();

    // GEMM2: we[128x64] = e[128x64] @ wW[64x64]
    bf16x8 bw0 = *(const bf16x8*)(wWfrag + (((t * 2 + 0) * 4 + w) * 64 + lane) * 8);
    bf16x8 bw1 = *(const bf16x8*)(wWfrag + (((t * 2 + 1) * 4 + w) * 64 + lane) * 8);
    f32x4 d2[8];
    #pragma unroll
    for (int rt = 0; rt < 8; ++rt) {
        bf16x8 a0 = *(const bf16x8*)&lds_e[((0 + kc) * EPB + rt * 16 + cr) * 8];
        bf16x8 a1 = *(const bf16x8*)&lds_e[((4 + kc) * EPB + rt * 16 + cr) * 8];
        f32x4 acc = __builtin_amdgcn_mfma_f32_16x16x32_bf16(a0, bw0, zero4, 0, 0, 0);
        d2[rt] = __builtin_amdgcn_mfma_f32_16x16x32_bf16(a1, bw1, acc, 0, 0, 0);
    }
    __syncthreads();   // all waves done reading lds_e; msg may overwrite

    // epilogue: silu, gather hx[sender], write msg to LDS (swizzled, 2-way free)
    float wbc = w_b[t * 64 + col];
    #pragma unroll
    for (int rt = 0; rt < 8; ++rt) {
        #pragma unroll
        for (int r = 0; r < 4; ++r) {
            int row = rt * 16 + kc * 4 + r;
            float m = 0.f;
            if (e0 + row < nE) {
                float we = silu_f(d2[rt][r] + wbc);
                m = we * hx[sidx[row] * TPSx + col];
            }
            msg[row * 64 + (col ^ (kc << 4))] = m;
        }
    }
    __syncthreads();

    // segmented reduction over receiver-sorted rows: 4 quarters x 64 cols
    {
        int colA = tid & 63;
        int q = tid >> 6;
        int base = q * 32;
        float acc = 0.f;
        int cur = ridx[base];
        for (int i = 0; i < 32; ++i) {
            int row = base + i;
            float v = msg[row * 64 + (colA ^ (((row >> 2) & 3) << 4))];
            int rr = ridx[row];          // wave-uniform
            if (rr != cur) {
                atomicAdd(&zt[cur * 64 + colA], acc);
                cur = rr; acc = v;
            } else {
                acc += v;
            }
        }
        atomicAdd(&zt[cur * 64 + colA], acc);
    }
}

// ---------------- final kernel: g-subnets + residual ----------------
__global__ __launch_bounds__(128)
void final_kernel(const float* __restrict__ elec, const float* __restrict__ z,
                  const float* __restrict__ gWres, const float* __restrict__ gbres,
                  const float* __restrict__ gWz, const float* __restrict__ gbz,
                  float* __restrict__ out)
{
    __shared__ float xe[4 * 128];
    __shared__ float xz[3 * 4 * 64];
    int b = blockIdx.x;     // 0..191
    int tid = threadIdx.x;  // 0..127
    int row0 = b * 4;
    for (int i = tid; i < 4 * 128; i += 128)
        xe[i] = elec[row0 * 128 + i];
    for (int i = tid; i < 3 * 4 * 64; i += 128) {
        int t = i >> 8; int rr = (i >> 6) & 3; int k = i & 63;
        xz[i] = z[t * N_ELx * 64 + (row0 + rr) * 64 + k];
    }
    __syncthreads();

    int col = tid;
    float accr[4] = {0.f, 0.f, 0.f, 0.f};
    for (int k = 0; k < 128; ++k) {
        float wv = gWres[k * 128 + col];
        #pragma unroll
        for (int r = 0; r < 4; ++r) accr[r] += xe[r * 128 + k] * wv;
    }
    float o[4];
    float br = gbres[col];
    #pragma unroll
    for (int r = 0; r < 4; ++r) o[r] = silu_f(accr[r] + br) + xe[r * 128 + col];

    for (int t = 0; t < 3; ++t) {
        float accz[4] = {0.f, 0.f, 0.f, 0.f};
        for (int k = 0; k < 64; ++k) {
            float wv = gWz[(t * 64 + k) * 128 + col];
            #pragma unroll
            for (int r = 0; r < 4; ++r) accz[r] += xz[t * 256 + r * 64 + k] * wv;
        }
        float bz = gbz[t * 128 + col];
        #pragma unroll
        for (int r = 0; r < 4; ++r) o[r] += silu_f(accz[r] + bz);
    }
    #pragma unroll
    for (int r = 0; r < 4; ++r) out[(row0 + r) * 128 + col] = o[r];
}

extern "C" void kernel_launch(void* const* d_in, const int* in_sizes, int n_in,
                              void* d_out, int out_size, void* d_ws, size_t ws_size,
                              hipStream_t stream)
{
    const float* elec   = (const float*)d_in[0];
    const float* nuclei = (const float*)d_in[1];
    const float* feat0  = (const float*)d_in[2];
    const float* feat1  = (const float*)d_in[3];
    const float* feat2  = (const float*)d_in[4];
    const int*   s0     = (const int*)d_in[5];
    const int*   r0     = (const int*)d_in[6];
    const int*   s1     = (const int*)d_in[7];
    const int*   r1     = (const int*)d_in[8];
    const int*   s2     = (const int*)d_in[9];
    const int*   r2     = (const int*)d_in[10];
    const float* u_W    = (const float*)d_in[11];
    const float* u_b    = (const float*)d_in[12];
    const float* w_W    = (const float*)d_in[13];
    const float* w_b    = (const float*)d_in[14];
    const float* hWee   = (const float*)d_in[15];
    const float* hbee   = (const float*)d_in[16];
    const float* hWne   = (const float*)d_in[17];
    const float* hbne   = (const float*)d_in[18];
    const float* gWres  = (const float*)d_in[19];
    const float* gbres  = (const float*)d_in[20];
    const float* gWz    = (const float*)d_in[21];
    const float* gbz    = (const float*)d_in[22];
    float* out = (float*)d_out;

    char* ws = (char*)d_ws;
    float* hx0    = (float*)(ws + 0);
    float* hx1    = (float*)(ws + 196608);
    float* hxn    = (float*)(ws + 393216);
    float* z      = (float*)(ws + 401408);        // 589824 B
    short* uWfrag = (short*)(ws + 991232);        // 12288 B
    short* wWfrag = (short*)(ws + 1003520);       // 24576 B
    int*   bins   = (int*)(ws + 1028096);         // 9216 B
    int*   cursor = (int*)(ws + 1037312);         // 9216 B
    int*   perm   = (int*)(ws + 1046528);         // 2454528 B

    int n0 = in_sizes[2] / EDGE_INx;
    int n1 = in_sizes[3] / EDGE_INx;
    int n2 = in_sizes[4] / EDGE_INx;
    int nb0 = (n0 + EPB - 1) / EPB;
    int nb1 = (n1 + EPB - 1) / EPB;
    int nb2 = (n2 + EPB - 1) / EPB;

    hipMemsetAsync(z, 0, 3 * N_ELx * TPSx * sizeof(float), stream);
    hipMemsetAsync(bins, 0, NBINS * sizeof(int), stream);
    prep_kernel<<<386, 256, 0, stream>>>(elec, nuclei, u_W, w_W, hWee, hbee,
                                         hWne, hbne, hx0, hx1, hxn, uWfrag, wWfrag);
    hist_kernel<<<64, 256, 0, stream>>>(r0, r1, r2, n0, n1, n2, bins);
    scan_kernel<<<1, 256, 0, stream>>>(bins, cursor);
    scatter_kernel<<<1024, 256, 0, stream>>>(r0, r1, r2, n0, n1, n2, cursor, perm);
    edge_kernel<<<nb0 + nb1 + nb2, 256, 0, stream>>>(
        feat0, feat1, feat2, s0, s1, s2, r0, r1, r2,
        u_b, w_b, hx0, hx1, hxn, uWfrag, wWfrag, perm, z,
        n0, n1, n2, nb0, nb1);
    final_kernel<<<192, 128, 0, stream>>>(elec, z, gWres, gbres, gWz, gbz, out);
}

// Round 3
// 152.572 us; speedup vs baseline: 1.7052x; 1.7052x over previous
//
#include <hip/hip_runtime.h>
#include <hip/hip_bf16.h>
#include <stdint.h>

#define N_ELx 768
#define EMBx 128
#define TPSx 64
#define EDGE_INx 32
#define EPB 128
#define NBINS 2304   // 3 types * 768 receivers
#define NB_SORT 96

typedef __attribute__((ext_vector_type(8))) short bf16x8;
typedef __attribute__((ext_vector_type(4))) float f32x4;

__device__ __forceinline__ short f2bf(float f) {
    union { float f; uint32_t u; } v; v.f = f;
    uint32_t u = v.u;
    uint32_t r = (u + 0x7FFFu + ((u >> 16) & 1u)) >> 16;
    return (short)r;
}

__device__ __forceinline__ float silu_f(float x) {
    return x / (1.0f + __expf(-x));
}

// ---------------- prep kernel: hx tables + B-fragment packing ----------------
__global__ __launch_bounds__(256)
void prep_kernel(const float* __restrict__ elec, const float* __restrict__ nuclei,
                 const float* __restrict__ uW, const float* __restrict__ wW,
                 const float* __restrict__ hWee, const float* __restrict__ hbee,
                 const float* __restrict__ hWne, const float* __restrict__ hbne,
                 float* __restrict__ hx0, float* __restrict__ hx1, float* __restrict__ hxn,
                 short* __restrict__ uWfrag, short* __restrict__ wWfrag)
{
    int b = blockIdx.x;
    int tid = threadIdx.x;
    if (b < 384) {
        // hx0 / hx1: silu(E @ hWee[t] + hbee[t]),  768x128 @ 128x64
        int t = b / 192;
        int rb = b % 192;
        int lr = tid >> 6;       // 0..3 (one row per wave)
        int col = tid & 63;
        int row = rb * 4 + lr;
        const float* W = hWee + t * 128 * 64;
        float acc = 0.f;
        for (int k = 0; k < 128; ++k)
            acc += elec[row * 128 + k] * W[k * 64 + col];
        float v = silu_f(acc + hbee[t * 64 + col]);
        (t == 0 ? hx0 : hx1)[row * 64 + col] = v;
    } else if (b == 384) {
        // hxn: silu(nuclei @ hWne + hbne), 32x64 @ 64x64
        int lr = tid >> 6, col = tid & 63;
        for (int i = 0; i < 8; ++i) {
            int row = lr * 8 + i;
            float acc = 0.f;
            for (int k = 0; k < 64; ++k)
                acc += nuclei[row * 64 + k] * hWne[k * 64 + col];
            hxn[row * 64 + col] = silu_f(acc + hbne[col]);
        }
    } else {
        // MFMA B-fragment packing (16x16x32: lane l holds B[k][col],
        // col = ct*16 + (l&15), k = (l>>4)*8 + j)
        for (int idx = tid; idx < 3 * 4 * 64; idx += 256) {
            int lane = idx & 63, ct = (idx >> 6) & 3, ty = idx >> 8;
            for (int j = 0; j < 8; ++j) {
                int k = (lane >> 4) * 8 + j, col = ct * 16 + (lane & 15);
                uWfrag[idx * 8 + j] = f2bf(uW[(ty * 32 + k) * 64 + col]);
            }
        }
        for (int idx = tid; idx < 3 * 2 * 4 * 64; idx += 256) {
            int lane = idx & 63, ct = (idx >> 6) & 3, ks = (idx >> 8) & 1, ty = idx >> 9;
            for (int j = 0; j < 8; ++j) {
                int k = ks * 32 + (lane >> 4) * 8 + j, col = ct * 16 + (lane & 15);
                wWfrag[idx * 8 + j] = f2bf(wW[(ty * 64 + k) * 64 + col]);
            }
        }
    }
}

// ---------------- sort: contention-free counting sort by (type, receiver) ----
__device__ __forceinline__ void decode_edge(int i, int n0, int n1,
                                            const int* __restrict__ r0,
                                            const int* __restrict__ r1,
                                            const int* __restrict__ r2,
                                            int& j, int& bin)
{
    int t;
    if (i < n0)            { t = 0; j = i; }
    else if (i < n0 + n1)  { t = 1; j = i - n0; }
    else                   { t = 2; j = i - n0 - n1; }
    int rv = (t == 0 ? r0 : (t == 1 ? r1 : r2))[j];
    bin = t * 768 + rv;
}

__global__ __launch_bounds__(256)
void blockhist_kernel(const int* __restrict__ r0, const int* __restrict__ r1,
                      const int* __restrict__ r2,
                      int n0, int n1, int n2, int* __restrict__ blockHist)
{
    __shared__ int h[NBINS];
    int tid = threadIdx.x, b = blockIdx.x;
    for (int i = tid; i < NBINS; i += 256) h[i] = 0;
    __syncthreads();
    int total = n0 + n1 + n2;
    int chunk = (total + NB_SORT - 1) / NB_SORT;
    int start = b * chunk, end = min(start + chunk, total);
    for (int i = start + tid; i < end; i += 256) {
        int j, bin;
        decode_edge(i, n0, n1, r0, r1, r2, j, bin);
        atomicAdd(&h[bin], 1);
    }
    __syncthreads();
    for (int i = tid; i < NBINS; i += 256)
        blockHist[i * NB_SORT + b] = h[i];
}

__global__ __launch_bounds__(256)
void binscan_kernel(int* __restrict__ blockHist, int* __restrict__ binTotal)
{
    int bin = blockIdx.x * 256 + threadIdx.x;   // 9 blocks x 256 = 2304
    int* p = blockHist + bin * NB_SORT;
    int run = 0;
    for (int b = 0; b < NB_SORT; ++b) { int v = p[b]; p[b] = run; run += v; }
    binTotal[bin] = run;
}

__global__ __launch_bounds__(256)
void scan_kernel(const int* __restrict__ bins, int* __restrict__ cursor)
{
    __shared__ int part[256];
    int tid = threadIdx.x;
    int l[9]; int s = 0;
    #pragma unroll
    for (int j = 0; j < 9; ++j) { l[j] = bins[tid * 9 + j]; s += l[j]; }
    part[tid] = s;
    __syncthreads();
    for (int off = 1; off < 256; off <<= 1) {
        int v = (tid >= off) ? part[tid - off] : 0;
        __syncthreads();
        part[tid] += v;
        __syncthreads();
    }
    int run = (tid == 0) ? 0 : part[tid - 1];
    #pragma unroll
    for (int j = 0; j < 9; ++j) { cursor[tid * 9 + j] = run; run += l[j]; }
}

__global__ __launch_bounds__(256)
void scatter2_kernel(const int* __restrict__ r0, const int* __restrict__ r1,
                     const int* __restrict__ r2,
                     int n0, int n1, int n2,
                     const int* __restrict__ blockHist,
                     const int* __restrict__ binStart,
                     int* __restrict__ perm)
{
    __shared__ int cursor[NBINS];
    int tid = threadIdx.x, b = blockIdx.x;
    for (int i = tid; i < NBINS; i += 256)
        cursor[i] = binStart[i] + blockHist[i * NB_SORT + b];
    __syncthreads();
    int total = n0 + n1 + n2;
    int chunk = (total + NB_SORT - 1) / NB_SORT;
    int start = b * chunk, end = min(start + chunk, total);
    for (int i = start + tid; i < end; i += 256) {
        int j, bin;
        decode_edge(i, n0, n1, r0, r1, r2, j, bin);
        int pos = atomicAdd(&cursor[bin], 1);   // LDS atomic — fast
        perm[pos] = j;
    }
}

// ---------------- edge kernel: receiver-sorted, LDS-aggregated scatter --------
__global__ __launch_bounds__(256)
void edge_kernel(const float* __restrict__ feat0, const float* __restrict__ feat1,
                 const float* __restrict__ feat2,
                 const int* __restrict__ s0, const int* __restrict__ s1, const int* __restrict__ s2,
                 const int* __restrict__ r0, const int* __restrict__ r1, const int* __restrict__ r2,
                 const float* __restrict__ u_b, const float* __restrict__ w_b,
                 const float* __restrict__ hx0, const float* __restrict__ hx1,
                 const float* __restrict__ hxn,
                 const short* __restrict__ uWfrag, const short* __restrict__ wWfrag,
                 const int* __restrict__ perm,
                 float* __restrict__ z,
                 int n0, int n1, int n2, int nb0, int nb1)
{
    // LDS: msg[128][64] f32 (32KB) overlays a1 (8KB @0) + e (16KB @8KB)
    __shared__ __align__(16) char smem[32768 + 1024];
    short* lds_a1 = (short*)smem;              // [4][128][8] bf16
    short* lds_e  = (short*)(smem + 8192);     // [8][128][8] bf16
    float* msg    = (float*)smem;              // [128][64] f32 (after GEMM2)
    int* sidx = (int*)(smem + 32768);
    int* ridx = sidx + 128;

    int b = blockIdx.x;
    int t; const float* feat; const int* sn; const int* rc; const float* hx; int nE;
    if (b < nb0)            { t = 0; feat = feat0; sn = s0; rc = r0; hx = hx0; nE = n0; }
    else if (b < nb0 + nb1) { t = 1; b -= nb0; feat = feat1; sn = s1; rc = r1; hx = hx1; nE = n1; }
    else                    { t = 2; b -= nb0 + nb1; feat = feat2; sn = s2; rc = r2; hx = hxn; nE = n2; }
    int e0 = b * EPB;
    int t_off = (t == 0) ? 0 : (t == 1 ? n0 : n0 + n1);
    float* zt = z + t * (N_ELx * TPSx);

    int tid = threadIdx.x;
    // stage feat -> LDS (bf16, MFMA-A chunk layout), via receiver-sorted perm
    {
        int row = tid >> 1, half = tid & 1;
        bool ok = (e0 + row) < nE;
        int pe = ok ? perm[t_off + e0 + row] : 0;
        if (half == 0) sidx[row] = sn[pe];
        else           ridx[row] = ok ? rc[pe] : 0;
        const float4* src = (const float4*)(feat + (size_t)pe * EDGE_INx + half * 16);
        #pragma unroll
        for (int c = 0; c < 2; ++c) {
            float4 fa, fb;
            if (ok) { fa = src[c * 2 + 0]; fb = src[c * 2 + 1]; }
            else    { fa = make_float4(0,0,0,0); fb = make_float4(0,0,0,0); }
            bf16x8 v;
            v[0] = f2bf(fa.x); v[1] = f2bf(fa.y); v[2] = f2bf(fa.z); v[3] = f2bf(fa.w);
            v[4] = f2bf(fb.x); v[5] = f2bf(fb.y); v[6] = f2bf(fb.z); v[7] = f2bf(fb.w);
            int kc = half * 2 + c;
            *(bf16x8*)&lds_a1[(kc * EPB + row) * 8] = v;
        }
    }
    __syncthreads();

    int lane = tid & 63;
    int w = tid >> 6;          // wave id = output col-tile
    int kc = lane >> 4;        // 0..3
    int cr = lane & 15;
    int col = w * 16 + cr;

    f32x4 zero4 = {0.f, 0.f, 0.f, 0.f};

    // GEMM1: e[128x64] = feat[128x32] @ uW[32x64]
    bf16x8 bu = *(const bf16x8*)(uWfrag + ((t * 4 + w) * 64 + lane) * 8);
    float ubc = u_b[t * 64 + col];
    f32x4 d1[8];
    #pragma unroll
    for (int rt = 0; rt < 8; ++rt) {
        bf16x8 a = *(const bf16x8*)&lds_a1[(kc * EPB + rt * 16 + cr) * 8];
        d1[rt] = __builtin_amdgcn_mfma_f32_16x16x32_bf16(a, bu, zero4, 0, 0, 0);
    }
    // silu + write e to LDS (A-layout for GEMM2; k-dim of GEMM2 = col of e)
    {
        int ks = col >> 5, c2 = (col >> 3) & 3, j = col & 7;
        short* ebase = &lds_e[((ks * 4 + c2) * EPB) * 8 + j];
        #pragma unroll
        for (int rt = 0; rt < 8; ++rt) {
            #pragma unroll
            for (int r = 0; r < 4; ++r) {
                int row = rt * 16 + kc * 4 + r;
                ebase[row * 8] = f2bf(silu_f(d1[rt][r] + ubc));
            }
        }
    }
    __syncthreads();

    // GEMM2: we[128x64] = e[128x64] @ wW[64x64]
    bf16x8 bw0 = *(const bf16x8*)(wWfrag + (((t * 2 + 0) * 4 + w) * 64 + lane) * 8);
    bf16x8 bw1 = *(const bf16x8*)(wWfrag + (((t * 2 + 1) * 4 + w) * 64 + lane) * 8);
    f32x4 d2[8];
    #pragma unroll
    for (int rt = 0; rt < 8; ++rt) {
        bf16x8 a0 = *(const bf16x8*)&lds_e[((0 + kc) * EPB + rt * 16 + cr) * 8];
        bf16x8 a1 = *(const bf16x8*)&lds_e[((4 + kc) * EPB + rt * 16 + cr) * 8];
        f32x4 acc = __builtin_amdgcn_mfma_f32_16x16x32_bf16(a0, bw0, zero4, 0, 0, 0);
        d2[rt] = __builtin_amdgcn_mfma_f32_16x16x32_bf16(a1, bw1, acc, 0, 0, 0);
    }
    __syncthreads();   // all waves done reading lds_e; msg may overwrite

    // epilogue: silu, gather hx[sender], write msg to LDS (swizzled, 2-way free)
    float wbc = w_b[t * 64 + col];
    #pragma unroll
    for (int rt = 0; rt < 8; ++rt) {
        #pragma unroll
        for (int r = 0; r < 4; ++r) {
            int row = rt * 16 + kc * 4 + r;
            float m = 0.f;
            if (e0 + row < nE) {
                float we = silu_f(d2[rt][r] + wbc);
                m = we * hx[sidx[row] * TPSx + col];
            }
            msg[row * 64 + (col ^ (kc << 4))] = m;
        }
    }
    __syncthreads();

    // segmented reduction over receiver-sorted rows: 4 quarters x 64 cols
    {
        int colA = tid & 63;
        int q = tid >> 6;
        int base = q * 32;
        float acc = 0.f;
        int cur = ridx[base];
        for (int i = 0; i < 32; ++i) {
            int row = base + i;
            float v = msg[row * 64 + (colA ^ (((row >> 2) & 3) << 4))];
            int rr = ridx[row];          // wave-uniform
            if (rr != cur) {
                atomicAdd(&zt[cur * 64 + colA], acc);
                cur = rr; acc = v;
            } else {
                acc += v;
            }
        }
        atomicAdd(&zt[cur * 64 + colA], acc);
    }
}

// ---------------- final kernel: g-subnets + residual ----------------
__global__ __launch_bounds__(128)
void final_kernel(const float* __restrict__ elec, const float* __restrict__ z,
                  const float* __restrict__ gWres, const float* __restrict__ gbres,
                  const float* __restrict__ gWz, const float* __restrict__ gbz,
                  float* __restrict__ out)
{
    __shared__ float xe[4 * 128];
    __shared__ float xz[3 * 4 * 64];
    int b = blockIdx.x;     // 0..191
    int tid = threadIdx.x;  // 0..127
    int row0 = b * 4;
    for (int i = tid; i < 4 * 128; i += 128)
        xe[i] = elec[row0 * 128 + i];
    for (int i = tid; i < 3 * 4 * 64; i += 128) {
        int t = i >> 8; int rr = (i >> 6) & 3; int k = i & 63;
        xz[i] = z[t * N_ELx * 64 + (row0 + rr) * 64 + k];
    }
    __syncthreads();

    int col = tid;
    float accr[4] = {0.f, 0.f, 0.f, 0.f};
    for (int k = 0; k < 128; ++k) {
        float wv = gWres[k * 128 + col];
        #pragma unroll
        for (int r = 0; r < 4; ++r) accr[r] += xe[r * 128 + k] * wv;
    }
    float o[4];
    float br = gbres[col];
    #pragma unroll
    for (int r = 0; r < 4; ++r) o[r] = silu_f(accr[r] + br) + xe[r * 128 + col];

    for (int t = 0; t < 3; ++t) {
        float accz[4] = {0.f, 0.f, 0.f, 0.f};
        for (int k = 0; k < 64; ++k) {
            float wv = gWz[(t * 64 + k) * 128 + col];
            #pragma unroll
            for (int r = 0; r < 4; ++r) accz[r] += xz[t * 256 + r * 64 + k] * wv;
        }
        float bz = gbz[t * 128 + col];
        #pragma unroll
        for (int r = 0; r < 4; ++r) o[r] += silu_f(accz[r] + bz);
    }
    #pragma unroll
    for (int r = 0; r < 4; ++r) out[(row0 + r) * 128 + col] = o[r];
}

extern "C" void kernel_launch(void* const* d_in, const int* in_sizes, int n_in,
                              void* d_out, int out_size, void* d_ws, size_t ws_size,
                              hipStream_t stream)
{
    const float* elec   = (const float*)d_in[0];
    const float* nuclei = (const float*)d_in[1];
    const float* feat0  = (const float*)d_in[2];
    const float* feat1  = (const float*)d_in[3];
    const float* feat2  = (const float*)d_in[4];
    const int*   s0     = (const int*)d_in[5];
    const int*   r0     = (const int*)d_in[6];
    const int*   s1     = (const int*)d_in[7];
    const int*   r1     = (const int*)d_in[8];
    const int*   s2     = (const int*)d_in[9];
    const int*   r2     = (const int*)d_in[10];
    const float* u_W    = (const float*)d_in[11];
    const float* u_b    = (const float*)d_in[12];
    const float* w_W    = (const float*)d_in[13];
    const float* w_b    = (const float*)d_in[14];
    const float* hWee   = (const float*)d_in[15];
    const float* hbee   = (const float*)d_in[16];
    const float* hWne   = (const float*)d_in[17];
    const float* hbne   = (const float*)d_in[18];
    const float* gWres  = (const float*)d_in[19];
    const float* gbres  = (const float*)d_in[20];
    const float* gWz    = (const float*)d_in[21];
    const float* gbz    = (const float*)d_in[22];
    float* out = (float*)d_out;

    char* ws = (char*)d_ws;
    float* hx0      = (float*)(ws + 0);           // 196608
    float* hx1      = (float*)(ws + 196608);      // 196608
    float* hxn      = (float*)(ws + 393216);      // 8192
    float* z        = (float*)(ws + 401408);      // 589824
    short* uWfrag   = (short*)(ws + 991232);      // 12288
    short* wWfrag   = (short*)(ws + 1003520);     // 24576
    int*   binTotal = (int*)(ws + 1028096);       // 9216
    int*   binStart = (int*)(ws + 1037312);       // 9216
    int*   perm     = (int*)(ws + 1046528);       // 2454528
    int*   blockHist= (int*)(ws + 3501056);       // 884736  (end: 4385792)

    int n0 = in_sizes[2] / EDGE_INx;
    int n1 = in_sizes[3] / EDGE_INx;
    int n2 = in_sizes[4] / EDGE_INx;
    int nb0 = (n0 + EPB - 1) / EPB;
    int nb1 = (n1 + EPB - 1) / EPB;
    int nb2 = (n2 + EPB - 1) / EPB;

    hipMemsetAsync(z, 0, 3 * N_ELx * TPSx * sizeof(float), stream);
    prep_kernel<<<386, 256, 0, stream>>>(elec, nuclei, u_W, w_W, hWee, hbee,
                                         hWne, hbne, hx0, hx1, hxn, uWfrag, wWfrag);
    blockhist_kernel<<<NB_SORT, 256, 0, stream>>>(r0, r1, r2, n0, n1, n2, blockHist);
    binscan_kernel<<<NBINS / 256, 256, 0, stream>>>(blockHist, binTotal);
    scan_kernel<<<1, 256, 0, stream>>>(binTotal, binStart);
    scatter2_kernel<<<NB_SORT, 256, 0, stream>>>(r0, r1, r2, n0, n1, n2,
                                                 blockHist, binStart, perm);
    edge_kernel<<<nb0 + nb1 + nb2, 256, 0, stream>>>(
        feat0, feat1, feat2, s0, s1, s2, r0, r1, r2,
        u_b, w_b, hx0, hx1, hxn, uWfrag, wWfrag, perm, z,
        n0, n1, n2, nb0, nb1);
    final_kernel<<<192, 128, 0, stream>>>(elec, z, gWres, gbres, gWz, gbz, out);
}